// Round 1
// baseline (11494.909 us; speedup 1.0000x reference)
//
#include <hip/hip_runtime.h>
#include <math.h>

#define Bc 2
#define Ec 100000
#define Vc 12500
#define Dc 128
#define Lc 4
#define TE 32

// ---------------- timestep embedding MLP (tiny: B=2) ----------------
__global__ void t_emb_kernel(const int* __restrict__ n,
                             const float* __restrict__ te_w1, const float* __restrict__ te_b1,
                             const float* __restrict__ te_w2, const float* __restrict__ te_b2,
                             float* __restrict__ t_emb) {
    const int b = blockIdx.x;
    const int t = threadIdx.x; // 128 threads
    __shared__ float emb[Dc];
    __shared__ float hid[4 * Dc];
    const float nf = (float)n[b];
    const int half = Dc / 2;
    {
        int j = (t < half) ? t : (t - half);
        float freq = expf(-logf(10000.0f) * (float)j / (float)half);
        float arg = nf * freq;
        emb[t] = (t < half) ? sinf(arg) : cosf(arg);
    }
    __syncthreads();
    for (int jj = 0; jj < 4; ++jj) {
        int c = t + jj * Dc; // 0..511
        float acc = te_b1[c];
        for (int k = 0; k < Dc; ++k) acc += emb[k] * te_w1[k * (4 * Dc) + c];
        hid[c] = acc / (1.0f + expf(-acc)); // silu
    }
    __syncthreads();
    float acc = te_b2[t];
    for (int k = 0; k < 4 * Dc; ++k) acc += hid[k] * te_w2[k * Dc + t];
    t_emb[b * Dc + t] = acc;
}

// ---------------- input projection + t_emb add ----------------
__global__ void input_proj_kernel(const float* __restrict__ delta,
                                  const float* __restrict__ w_in, const float* __restrict__ b_in,
                                  const float* __restrict__ t_emb,
                                  float* __restrict__ h) {
    int idx = blockIdx.x * blockDim.x + threadIdx.x;
    const int total = Bc * Ec * (Dc / 4);
    if (idx >= total) return;
    int dq = idx & (Dc / 4 - 1); // 0..31
    int be = idx >> 5;
    int b = be / Ec;
    const float* dd = delta + (size_t)be * 3;
    float d0 = dd[0], d1 = dd[1], d2 = dd[2];
    float4 acc = ((const float4*)b_in)[dq];
    float4 te = ((const float4*)t_emb)[b * (Dc / 4) + dq];
    float4 w0 = ((const float4*)w_in)[dq];
    float4 w1 = ((const float4*)w_in)[(Dc / 4) + dq];
    float4 w2 = ((const float4*)w_in)[2 * (Dc / 4) + dq];
    acc.x += te.x + d0 * w0.x + d1 * w1.x + d2 * w2.x;
    acc.y += te.y + d0 * w0.y + d1 * w1.y + d2 * w2.y;
    acc.z += te.z + d0 * w0.z + d1 * w1.z + d2 * w2.z;
    acc.w += te.w + d0 * w0.w + d1 * w1.w + d2 * w2.w;
    ((float4*)h)[idx] = acc;
}

// ---------------- zero workspace (graph-capture-safe) ----------------
__global__ void zero_kernel(float4* __restrict__ p, int n4) {
    int i = blockIdx.x * blockDim.x + threadIdx.x;
    if (i < n4) p[i] = make_float4(0.f, 0.f, 0.f, 0.f);
}

// ---------------- scatter-add edges -> vertices ----------------
__global__ void scatter_kernel(const float* __restrict__ h,
                               const int* __restrict__ src, const int* __restrict__ dst,
                               float* __restrict__ vf) {
    int idx = blockIdx.x * blockDim.x + threadIdx.x;
    const int total = Bc * Ec * (Dc / 4);
    if (idx >= total) return;
    int dq = idx & 31;
    int be = idx >> 5;
    int b = be / Ec;
    int e = be - b * Ec;
    float4 hv = ((const float4*)h)[idx];
    int s = src[e], d = dst[e];
    float* ps = vf + ((size_t)(b * Vc + s)) * Dc + dq * 4;
    float* pd = vf + ((size_t)(b * Vc + d)) * Dc + dq * 4;
    atomicAdd(ps + 0, hv.x); atomicAdd(ps + 1, hv.y);
    atomicAdd(ps + 2, hv.z); atomicAdd(ps + 3, hv.w);
    atomicAdd(pd + 0, hv.x); atomicAdd(pd + 1, hv.y);
    atomicAdd(pd + 2, hv.z); atomicAdd(pd + 3, hv.w);
}

// ---------------- fused edge MLP layer ----------------
// block = 256 threads, TE=32 edges/block. thread t: row r = t>>3, colgroup cg = t&7 (16 cols each)
__launch_bounds__(256)
__global__ void edge_layer_kernel(float* __restrict__ h,
                                  const float* __restrict__ vf,
                                  const int* __restrict__ src, const int* __restrict__ dst,
                                  const float* __restrict__ W1, const float* __restrict__ b1,
                                  const float* __restrict__ ln_g, const float* __restrict__ ln_b,
                                  const float* __restrict__ W2, const float* __restrict__ b2,
                                  const float* __restrict__ ng, const float* __restrict__ nb) {
    __shared__ float xin[TE][260];  // 256 + pad4 -> conflict-free 8-row reads
    __shared__ float x1s[TE][132];  // 128 + pad4
    const int t = threadIdx.x;
    const int r = t >> 3;
    const int cg = t & 7;
    const int c0 = cg * 16;
    const int be = blockIdx.x * TE + r;
    const int b = be / Ec;
    const int e = be - b * Ec;
    const int vs = src[e], vd = dst[e];

    // stage gathered row [vf[src] | vf[dst]] into LDS
    {
        const float4* ps = (const float4*)(vf + ((size_t)(b * Vc + vs)) * Dc);
        const float4* pd = (const float4*)(vf + ((size_t)(b * Vc + vd)) * Dc);
        float4* xrowA = (float4*)(&xin[r][0]);    // row stride 1040B = 65*16, aligned
        float4* xrowB = (float4*)(&xin[r][128]);
        #pragma unroll
        for (int q = 0; q < 4; ++q) xrowA[cg * 4 + q] = ps[cg * 4 + q];
        #pragma unroll
        for (int q = 0; q < 4; ++q) xrowB[cg * 4 + q] = pd[cg * 4 + q];
    }
    __syncthreads();

    // GEMM1: x1 = xin @ W1 + b1   (256 -> 128), thread does 16 cols of 1 row
    float acc[16];
    {
        #pragma unroll
        for (int j = 0; j < 16; ++j) acc[j] = b1[c0 + j];
        const float4* W1v = (const float4*)W1;
        for (int k = 0; k < 2 * Dc; ++k) {
            float xk = xin[r][k];
            const float4* wrow = W1v + (size_t)k * (Dc / 4) + cg * 4;
            #pragma unroll
            for (int q = 0; q < 4; ++q) {
                float4 w = wrow[q];
                acc[q * 4 + 0] += xk * w.x; acc[q * 4 + 1] += xk * w.y;
                acc[q * 4 + 2] += xk * w.z; acc[q * 4 + 3] += xk * w.w;
            }
        }
    }
    // LN (over 128 cols, 8 threads/row) + silu, write to LDS
    {
        float s = 0.f, ss = 0.f;
        #pragma unroll
        for (int j = 0; j < 16; ++j) { s += acc[j]; ss += acc[j] * acc[j]; }
        #pragma unroll
        for (int m = 1; m < 8; m <<= 1) {
            s += __shfl_xor(s, m, 64);
            ss += __shfl_xor(ss, m, 64);
        }
        float mean = s * (1.0f / Dc);
        float var = ss * (1.0f / Dc) - mean * mean;
        float rstd = rsqrtf(var + 1e-5f);
        #pragma unroll
        for (int j = 0; j < 16; ++j) {
            float xh = (acc[j] - mean) * rstd * ln_g[c0 + j] + ln_b[c0 + j];
            acc[j] = xh / (1.0f + expf(-xh)); // silu
        }
        float4* xr = (float4*)(&x1s[r][c0]); // 528B row stride, 64B col offset: aligned
        #pragma unroll
        for (int q = 0; q < 4; ++q)
            xr[q] = make_float4(acc[q * 4 + 0], acc[q * 4 + 1], acc[q * 4 + 2], acc[q * 4 + 3]);
    }
    __syncthreads();

    // GEMM2: x2 = x1 @ W2 + b2 (128 -> 128)
    float acc2[16];
    {
        #pragma unroll
        for (int j = 0; j < 16; ++j) acc2[j] = b2[c0 + j];
        const float4* W2v = (const float4*)W2;
        for (int k = 0; k < Dc; ++k) {
            float xk = x1s[r][k];
            const float4* wrow = W2v + (size_t)k * (Dc / 4) + cg * 4;
            #pragma unroll
            for (int q = 0; q < 4; ++q) {
                float4 w = wrow[q];
                acc2[q * 4 + 0] += xk * w.x; acc2[q * 4 + 1] += xk * w.y;
                acc2[q * 4 + 2] += xk * w.z; acc2[q * 4 + 3] += xk * w.w;
            }
        }
    }
    // residual + LN -> h (in place; block owns its rows)
    {
        float4* hrow = (float4*)(h + (size_t)be * Dc + c0);
        float y[16];
        #pragma unroll
        for (int q = 0; q < 4; ++q) {
            float4 hv = hrow[q];
            y[q * 4 + 0] = hv.x + acc2[q * 4 + 0];
            y[q * 4 + 1] = hv.y + acc2[q * 4 + 1];
            y[q * 4 + 2] = hv.z + acc2[q * 4 + 2];
            y[q * 4 + 3] = hv.w + acc2[q * 4 + 3];
        }
        float s = 0.f, ss = 0.f;
        #pragma unroll
        for (int j = 0; j < 16; ++j) { s += y[j]; ss += y[j] * y[j]; }
        #pragma unroll
        for (int m = 1; m < 8; m <<= 1) {
            s += __shfl_xor(s, m, 64);
            ss += __shfl_xor(ss, m, 64);
        }
        float mean = s * (1.0f / Dc);
        float var = ss * (1.0f / Dc) - mean * mean;
        float rstd = rsqrtf(var + 1e-5f);
        #pragma unroll
        for (int q = 0; q < 4; ++q) {
            float4 o;
            o.x = (y[q * 4 + 0] - mean) * rstd * ng[c0 + q * 4 + 0] + nb[c0 + q * 4 + 0];
            o.y = (y[q * 4 + 1] - mean) * rstd * ng[c0 + q * 4 + 1] + nb[c0 + q * 4 + 1];
            o.z = (y[q * 4 + 2] - mean) * rstd * ng[c0 + q * 4 + 2] + nb[c0 + q * 4 + 2];
            o.w = (y[q * 4 + 3] - mean) * rstd * ng[c0 + q * 4 + 3] + nb[c0 + q * 4 + 3];
            hrow[q] = o;
        }
    }
}

// ---------------- output projection ----------------
__global__ void out_proj_kernel(const float* __restrict__ h,
                                const float* __restrict__ w_out, const float* __restrict__ b_out,
                                float* __restrict__ out) {
    int be = blockIdx.x * blockDim.x + threadIdx.x;
    if (be >= Bc * Ec) return;
    const float4* hp = (const float4*)(h + (size_t)be * Dc);
    float a0 = b_out[0], a1 = b_out[1], a2 = b_out[2];
    for (int q = 0; q < Dc / 4; ++q) {
        float4 v = hp[q];
        int k = q * 4;
        a0 += v.x * w_out[(k + 0) * 3 + 0] + v.y * w_out[(k + 1) * 3 + 0] +
              v.z * w_out[(k + 2) * 3 + 0] + v.w * w_out[(k + 3) * 3 + 0];
        a1 += v.x * w_out[(k + 0) * 3 + 1] + v.y * w_out[(k + 1) * 3 + 1] +
              v.z * w_out[(k + 2) * 3 + 1] + v.w * w_out[(k + 3) * 3 + 1];
        a2 += v.x * w_out[(k + 0) * 3 + 2] + v.y * w_out[(k + 1) * 3 + 2] +
              v.z * w_out[(k + 2) * 3 + 2] + v.w * w_out[(k + 3) * 3 + 2];
    }
    out[be * 3 + 0] = a0;
    out[be * 3 + 1] = a1;
    out[be * 3 + 2] = a2;
}

extern "C" void kernel_launch(void* const* d_in, const int* in_sizes, int n_in,
                              void* d_out, int out_size, void* d_ws, size_t ws_size,
                              hipStream_t stream) {
    const float* delta = (const float*)d_in[0];
    const int* n = (const int*)d_in[1];
    const int* edge_index = (const int*)d_in[2];
    // d_in[3] = num_vertices (compile-time constant Vc)
    const float* w_in = (const float*)d_in[4];
    const float* b_in = (const float*)d_in[5];
    const float* W1 = (const float*)d_in[6];
    const float* b1 = (const float*)d_in[7];
    const float* ln_g = (const float*)d_in[8];
    const float* ln_b = (const float*)d_in[9];
    const float* W2 = (const float*)d_in[10];
    const float* b2 = (const float*)d_in[11];
    const float* ng = (const float*)d_in[12];
    const float* nb = (const float*)d_in[13];
    const float* te_w1 = (const float*)d_in[14];
    const float* te_b1 = (const float*)d_in[15];
    const float* te_w2 = (const float*)d_in[16];
    const float* te_b2 = (const float*)d_in[17];
    const float* w_out = (const float*)d_in[18];
    const float* b_out = (const float*)d_in[19];
    float* out = (float*)d_out;

    char* ws = (char*)d_ws;
    float* t_emb = (float*)ws;                                      // 256 f
    float* h = (float*)(ws + 1024);                                 // B*E*D f = 102.4 MB
    float* vf = (float*)(ws + 1024 + (size_t)Bc * Ec * Dc * 4);     // B*V*D f = 12.8 MB

    const int* src = edge_index;
    const int* dst = edge_index + Ec;

    t_emb_kernel<<<Bc, Dc, 0, stream>>>(n, te_w1, te_b1, te_w2, te_b2, t_emb);

    {
        int total = Bc * Ec * (Dc / 4);
        input_proj_kernel<<<(total + 255) / 256, 256, 0, stream>>>(delta, w_in, b_in, t_emb, h);
    }

    for (int i = 0; i < Lc; ++i) {
        int n4 = Bc * Vc * Dc / 4;
        zero_kernel<<<(n4 + 255) / 256, 256, 0, stream>>>((float4*)vf, n4);
        int total = Bc * Ec * (Dc / 4);
        scatter_kernel<<<(total + 255) / 256, 256, 0, stream>>>(h, src, dst, vf);
        edge_layer_kernel<<<(Bc * Ec) / TE, 256, 0, stream>>>(
            h, vf, src, dst,
            W1 + (size_t)i * 2 * Dc * Dc, b1 + i * Dc,
            ln_g + i * Dc, ln_b + i * Dc,
            W2 + (size_t)i * Dc * Dc, b2 + i * Dc,
            ng + i * Dc, nb + i * Dc);
    }

    out_proj_kernel<<<(Bc * Ec + 255) / 256, 256, 0, stream>>>(h, w_out, b_out, out);
}

// Round 5
// 3630.173 us; speedup vs baseline: 3.1665x; 3.1665x over previous
//
#include <hip/hip_runtime.h>
#include <math.h>

#define Bc 2
#define Ec 100000
#define Vc 12500
#define Dc 128
#define Lc 4

typedef __attribute__((ext_vector_type(4))) float f32x4;
typedef __attribute__((ext_vector_type(8))) short short8s;
typedef __attribute__((ext_vector_type(8))) __bf16 bf16x8;

static __device__ __forceinline__ short f2bf(float f) {
    unsigned u = __builtin_bit_cast(unsigned, f);
    unsigned r = (u + 0x7FFFu + ((u >> 16) & 1u)) >> 16;  // RNE
    return (short)r;
}

static __device__ __forceinline__ f32x4 mfma16(short8s a, short8s b, f32x4 c) {
    return __builtin_amdgcn_mfma_f32_16x16x32_bf16(
        __builtin_bit_cast(bf16x8, a), __builtin_bit_cast(bf16x8, b), c, 0, 0, 0);
}

// ---------------- timestep embedding MLP (tiny: B=2) ----------------
__global__ void t_emb_kernel(const int* __restrict__ n,
                             const float* __restrict__ te_w1, const float* __restrict__ te_b1,
                             const float* __restrict__ te_w2, const float* __restrict__ te_b2,
                             float* __restrict__ t_emb) {
    const int b = blockIdx.x;
    const int t = threadIdx.x; // 128 threads
    __shared__ float emb[Dc];
    __shared__ float hid[4 * Dc];
    const float nf = (float)n[b];
    const int half = Dc / 2;
    {
        int j = (t < half) ? t : (t - half);
        float freq = expf(-logf(10000.0f) * (float)j / (float)half);
        float arg = nf * freq;
        emb[t] = (t < half) ? sinf(arg) : cosf(arg);
    }
    __syncthreads();
    for (int jj = 0; jj < 4; ++jj) {
        int c = t + jj * Dc;
        float acc = te_b1[c];
        for (int k = 0; k < Dc; ++k) acc += emb[k] * te_w1[k * (4 * Dc) + c];
        hid[c] = acc / (1.0f + expf(-acc));
    }
    __syncthreads();
    float acc = te_b2[t];
    for (int k = 0; k < 4 * Dc; ++k) acc += hid[k] * te_w2[k * Dc + t];
    t_emb[b * Dc + t] = acc;
}

// ---------------- input projection + t_emb add ----------------
__global__ void input_proj_kernel(const float* __restrict__ delta,
                                  const float* __restrict__ w_in, const float* __restrict__ b_in,
                                  const float* __restrict__ t_emb,
                                  float* __restrict__ h) {
    int idx = blockIdx.x * blockDim.x + threadIdx.x;
    const int total = Bc * Ec * (Dc / 4);
    if (idx >= total) return;
    int dq = idx & (Dc / 4 - 1);
    int be = idx >> 5;
    int b = be / Ec;
    const float* dd = delta + (size_t)be * 3;
    float d0 = dd[0], d1 = dd[1], d2 = dd[2];
    float4 acc = ((const float4*)b_in)[dq];
    float4 te = ((const float4*)t_emb)[b * (Dc / 4) + dq];
    float4 w0 = ((const float4*)w_in)[dq];
    float4 w1 = ((const float4*)w_in)[(Dc / 4) + dq];
    float4 w2 = ((const float4*)w_in)[2 * (Dc / 4) + dq];
    acc.x += te.x + d0 * w0.x + d1 * w1.x + d2 * w2.x;
    acc.y += te.y + d0 * w0.y + d1 * w1.y + d2 * w2.y;
    acc.z += te.z + d0 * w0.z + d1 * w1.z + d2 * w2.z;
    acc.w += te.w + d0 * w0.w + d1 * w1.w + d2 * w2.w;
    ((float4*)h)[idx] = acc;
}

// ---------------- zero workspace ----------------
__global__ void zero_kernel(float4* __restrict__ p, int n4) {
    int i = blockIdx.x * blockDim.x + threadIdx.x;
    if (i < n4) p[i] = make_float4(0.f, 0.f, 0.f, 0.f);
}

// ---------------- weight pre-convert: fp32 -> bf16 transposed ----------------
// w1t[l][n][k] = W1[l][k][n]  (n<128, k<256);  w2t[l][n][k] = W2[l][k][n]
__global__ void convert_w_kernel(const float* __restrict__ W1, const float* __restrict__ W2,
                                 short* __restrict__ w1t, short* __restrict__ w2t) {
    int idx = blockIdx.x * blockDim.x + threadIdx.x;
    if (idx < Lc * 128 * 256) {
        int l = idx / (128 * 256);
        int r = idx - l * (128 * 256);
        int nn = r >> 8;          // 0..127
        int k = r & 255;          // 0..255
        w1t[idx] = f2bf(W1[(size_t)l * 256 * 128 + k * 128 + nn]);
    }
    if (idx < Lc * 128 * 128) {
        int l = idx / (128 * 128);
        int r = idx - l * (128 * 128);
        int nn = r >> 7;
        int k = r & 127;
        w2t[idx] = f2bf(W2[(size_t)l * 128 * 128 + k * 128 + nn]);
    }
}

// ---------------- scatter-add edges -> vertices ----------------
__global__ void scatter_kernel(const float* __restrict__ h,
                               const int* __restrict__ src, const int* __restrict__ dst,
                               float* __restrict__ vf) {
    int idx = blockIdx.x * blockDim.x + threadIdx.x;
    const int total = Bc * Ec * (Dc / 4);
    if (idx >= total) return;
    int dq = idx & 31;
    int be = idx >> 5;
    int b = be / Ec;
    int e = be - b * Ec;
    float4 hv = ((const float4*)h)[idx];
    int s = src[e], d = dst[e];
    float* ps = vf + ((size_t)(b * Vc + s)) * Dc + dq * 4;
    float* pd = vf + ((size_t)(b * Vc + d)) * Dc + dq * 4;
    atomicAdd(ps + 0, hv.x); atomicAdd(ps + 1, hv.y);
    atomicAdd(ps + 2, hv.z); atomicAdd(ps + 3, hv.w);
    atomicAdd(pd + 0, hv.x); atomicAdd(pd + 1, hv.y);
    atomicAdd(pd + 2, hv.z); atomicAdd(pd + 3, hv.w);
}

// ---------------- fused edge MLP layer (MFMA bf16) ----------------
// Block: 256 threads = 4 waves, 64 edges (16 per wave, wave-private).
// Computes transposed GEMMs: Dp[n][m] = Wt[n][:] . x[m][:] so that
//   A-frag (Wt) and B-frag (x) are both 8-contiguous-k b128 loads,
//   and C/D lanes hold 4 contiguous feature idxs -> float4 h access + cheap LN.
#define XSTR 264   // xin row stride (bf16 elems): 256 + 8 pad
#define X1STR 136  // x1s row stride: 128 + 8 pad
__launch_bounds__(256, 3)
__global__ void edge_layer_kernel(float* __restrict__ h,
                                  const float* __restrict__ vf,
                                  const int* __restrict__ src, const int* __restrict__ dst,
                                  const short* __restrict__ w1t, const float* __restrict__ b1,
                                  const float* __restrict__ ln_g, const float* __restrict__ ln_b,
                                  const short* __restrict__ w2t, const float* __restrict__ b2,
                                  const float* __restrict__ ng, const float* __restrict__ nb) {
    __shared__ short xin[64][XSTR];
    __shared__ short x1s[64][X1STR];

    const int t = threadIdx.x;
    const int w = t >> 6;
    const int lane = t & 63;
    const int m0 = w * 16;          // wave's edge sub-tile
    const int r = lane & 15;
    const int g = lane >> 4;        // k-block / reg-group

    // ---- stage gathered rows [vf[src] | vf[dst]] -> bf16 LDS (wave does its own 16 rows)
    for (int it = 0; it < 16; ++it) {
        int m = m0 + it;
        int eg = blockIdx.x * 64 + m;
        int b = eg / Ec;
        int e = eg - b * Ec;
        int v = (lane < 32) ? src[e] : dst[e];
        const float4* vrow = (const float4*)(vf + ((size_t)(b * Vc + v)) * Dc);
        float4 x = vrow[lane & 31];
        short4 s4;
        s4.x = f2bf(x.x); s4.y = f2bf(x.y); s4.z = f2bf(x.z); s4.w = f2bf(x.w);
        *(short4*)&xin[m][4 * lane] = s4;
    }
    __syncthreads();

    // ---- GEMM1t: x1^T = W1^T (128x256) @ xin^T (256x16)
    f32x4 acc[8];
    #pragma unroll
    for (int nt = 0; nt < 8; ++nt) acc[nt] = (f32x4){0.f, 0.f, 0.f, 0.f};
    #pragma unroll 2
    for (int ks = 0; ks < 8; ++ks) {
        short8s bfrag = *(const short8s*)&xin[m0 + r][32 * ks + 8 * g];
        #pragma unroll
        for (int nt = 0; nt < 8; ++nt) {
            short8s afrag = *(const short8s*)(w1t + (size_t)(nt * 16 + r) * 256 + 32 * ks + 8 * g);
            acc[nt] = mfma16(afrag, bfrag, acc[nt]);
        }
    }

    // ---- bias + LN + silu; repack to bf16 LDS (row-major [m][k]) for GEMM2
    {
        float s = 0.f, ss = 0.f;
        #pragma unroll
        for (int nt = 0; nt < 8; ++nt) {
            const float4 bb = *(const float4*)&b1[nt * 16 + 4 * g];
            acc[nt][0] += bb.x; acc[nt][1] += bb.y; acc[nt][2] += bb.z; acc[nt][3] += bb.w;
            #pragma unroll
            for (int i = 0; i < 4; ++i) { float v = acc[nt][i]; s += v; ss += v * v; }
        }
        s += __shfl_xor(s, 16); ss += __shfl_xor(ss, 16);
        s += __shfl_xor(s, 32); ss += __shfl_xor(ss, 32);
        float mean = s * (1.0f / Dc);
        float var = ss * (1.0f / Dc) - mean * mean;
        float rstd = rsqrtf(var + 1e-5f);
        #pragma unroll
        for (int nt = 0; nt < 8; ++nt) {
            const float4 lg = *(const float4*)&ln_g[nt * 16 + 4 * g];
            const float4 lb = *(const float4*)&ln_b[nt * 16 + 4 * g];
            float o[4];
            #pragma unroll
            for (int i = 0; i < 4; ++i) {
                float gg = (i == 0) ? lg.x : (i == 1) ? lg.y : (i == 2) ? lg.z : lg.w;
                float bb = (i == 0) ? lb.x : (i == 1) ? lb.y : (i == 2) ? lb.z : lb.w;
                float xh = (acc[nt][i] - mean) * rstd * gg + bb;
                o[i] = xh / (1.0f + __expf(-xh));
            }
            short4 st;
            st.x = f2bf(o[0]); st.y = f2bf(o[1]); st.z = f2bf(o[2]); st.w = f2bf(o[3]);
            *(short4*)&x1s[m0 + r][nt * 16 + 4 * g] = st;
        }
    }
    __syncthreads();

    // ---- GEMM2t: x2^T = W2^T (128x128) @ x1^T (128x16)
    f32x4 acc2[8];
    #pragma unroll
    for (int nt = 0; nt < 8; ++nt) acc2[nt] = (f32x4){0.f, 0.f, 0.f, 0.f};
    #pragma unroll 2
    for (int ks = 0; ks < 4; ++ks) {
        short8s bfrag = *(const short8s*)&x1s[m0 + r][32 * ks + 8 * g];
        #pragma unroll
        for (int nt = 0; nt < 8; ++nt) {
            short8s afrag = *(const short8s*)(w2t + (size_t)(nt * 16 + r) * 128 + 32 * ks + 8 * g);
            acc2[nt] = mfma16(afrag, bfrag, acc2[nt]);
        }
    }

    // ---- bias + residual + LN -> h
    {
        float* hrow = h + (size_t)(blockIdx.x * 64 + m0 + r) * Dc;
        float s = 0.f, ss = 0.f;
        #pragma unroll
        for (int nt = 0; nt < 8; ++nt) {
            const float4 bb = *(const float4*)&b2[nt * 16 + 4 * g];
            const float4 hv = *(const float4*)(hrow + nt * 16 + 4 * g);
            acc2[nt][0] += bb.x + hv.x; acc2[nt][1] += bb.y + hv.y;
            acc2[nt][2] += bb.z + hv.z; acc2[nt][3] += bb.w + hv.w;
            #pragma unroll
            for (int i = 0; i < 4; ++i) { float v = acc2[nt][i]; s += v; ss += v * v; }
        }
        s += __shfl_xor(s, 16); ss += __shfl_xor(ss, 16);
        s += __shfl_xor(s, 32); ss += __shfl_xor(ss, 32);
        float mean = s * (1.0f / Dc);
        float var = ss * (1.0f / Dc) - mean * mean;
        float rstd = rsqrtf(var + 1e-5f);
        #pragma unroll
        for (int nt = 0; nt < 8; ++nt) {
            const float4 gv = *(const float4*)&ng[nt * 16 + 4 * g];
            const float4 bv = *(const float4*)&nb[nt * 16 + 4 * g];
            float4 o;
            o.x = (acc2[nt][0] - mean) * rstd * gv.x + bv.x;
            o.y = (acc2[nt][1] - mean) * rstd * gv.y + bv.y;
            o.z = (acc2[nt][2] - mean) * rstd * gv.z + bv.z;
            o.w = (acc2[nt][3] - mean) * rstd * gv.w + bv.w;
            *(float4*)(hrow + nt * 16 + 4 * g) = o;
        }
    }
}

// ---------------- output projection ----------------
__global__ void out_proj_kernel(const float* __restrict__ h,
                                const float* __restrict__ w_out, const float* __restrict__ b_out,
                                float* __restrict__ out) {
    int be = blockIdx.x * blockDim.x + threadIdx.x;
    if (be >= Bc * Ec) return;
    const float4* hp = (const float4*)(h + (size_t)be * Dc);
    float a0 = b_out[0], a1 = b_out[1], a2 = b_out[2];
    for (int q = 0; q < Dc / 4; ++q) {
        float4 v = hp[q];
        int k = q * 4;
        a0 += v.x * w_out[(k + 0) * 3 + 0] + v.y * w_out[(k + 1) * 3 + 0] +
              v.z * w_out[(k + 2) * 3 + 0] + v.w * w_out[(k + 3) * 3 + 0];
        a1 += v.x * w_out[(k + 0) * 3 + 1] + v.y * w_out[(k + 1) * 3 + 1] +
              v.z * w_out[(k + 2) * 3 + 1] + v.w * w_out[(k + 3) * 3 + 1];
        a2 += v.x * w_out[(k + 0) * 3 + 2] + v.y * w_out[(k + 1) * 3 + 2] +
              v.z * w_out[(k + 2) * 3 + 2] + v.w * w_out[(k + 3) * 3 + 2];
    }
    out[be * 3 + 0] = a0;
    out[be * 3 + 1] = a1;
    out[be * 3 + 2] = a2;
}

extern "C" void kernel_launch(void* const* d_in, const int* in_sizes, int n_in,
                              void* d_out, int out_size, void* d_ws, size_t ws_size,
                              hipStream_t stream) {
    const float* delta = (const float*)d_in[0];
    const int* n = (const int*)d_in[1];
    const int* edge_index = (const int*)d_in[2];
    const float* w_in = (const float*)d_in[4];
    const float* b_in = (const float*)d_in[5];
    const float* W1 = (const float*)d_in[6];
    const float* b1 = (const float*)d_in[7];
    const float* ln_g = (const float*)d_in[8];
    const float* ln_b = (const float*)d_in[9];
    const float* W2 = (const float*)d_in[10];
    const float* b2 = (const float*)d_in[11];
    const float* ng = (const float*)d_in[12];
    const float* nb = (const float*)d_in[13];
    const float* te_w1 = (const float*)d_in[14];
    const float* te_b1 = (const float*)d_in[15];
    const float* te_w2 = (const float*)d_in[16];
    const float* te_b2 = (const float*)d_in[17];
    const float* w_out = (const float*)d_in[18];
    const float* b_out = (const float*)d_in[19];
    float* out = (float*)d_out;

    char* ws = (char*)d_ws;
    float* t_emb = (float*)ws;                                       // 1 KB
    float* h = (float*)(ws + 1024);                                  // 102.4 MB
    float* vf = (float*)(ws + 1024 + (size_t)Bc * Ec * Dc * 4);      // 12.8 MB
    short* w1t = (short*)(ws + 1024 + (size_t)Bc * Ec * Dc * 4 + (size_t)Bc * Vc * Dc * 4);
    short* w2t = w1t + (size_t)Lc * 128 * 256;

    const int* src = edge_index;
    const int* dst = edge_index + Ec;

    t_emb_kernel<<<Bc, Dc, 0, stream>>>(n, te_w1, te_b1, te_w2, te_b2, t_emb);
    convert_w_kernel<<<(Lc * 128 * 256 + 255) / 256, 256, 0, stream>>>(W1, W2, w1t, w2t);

    {
        int total = Bc * Ec * (Dc / 4);
        input_proj_kernel<<<(total + 255) / 256, 256, 0, stream>>>(delta, w_in, b_in, t_emb, h);
    }

    for (int i = 0; i < Lc; ++i) {
        int n4 = Bc * Vc * Dc / 4;
        zero_kernel<<<(n4 + 255) / 256, 256, 0, stream>>>((float4*)vf, n4);
        int total = Bc * Ec * (Dc / 4);
        scatter_kernel<<<(total + 255) / 256, 256, 0, stream>>>(h, src, dst, vf);
        edge_layer_kernel<<<(Bc * Ec) / 64, 256, 0, stream>>>(
            h, vf, src, dst,
            w1t + (size_t)i * 128 * 256, b1 + i * Dc,
            ln_g + i * Dc, ln_b + i * Dc,
            w2t + (size_t)i * 128 * 128, b2 + i * Dc,
            ng + i * Dc, nb + i * Dc);
    }

    out_proj_kernel<<<(Bc * Ec + 255) / 256, 256, 0, stream>>>(h, w_out, b_out, out);
}

// Round 6
// 1145.666 us; speedup vs baseline: 10.0334x; 3.1686x over previous
//
#include <hip/hip_runtime.h>
#include <math.h>

#define Bc 2
#define Ec 100000
#define Vc 12500
#define Dc 128
#define Lc 4

typedef __attribute__((ext_vector_type(4))) float f32x4;
typedef __attribute__((ext_vector_type(8))) short short8s;
typedef __attribute__((ext_vector_type(8))) __bf16 bf16x8;

static __device__ __forceinline__ short f2bf(float f) {
    unsigned u = __builtin_bit_cast(unsigned, f);
    unsigned r = (u + 0x7FFFu + ((u >> 16) & 1u)) >> 16;  // RNE
    return (short)r;
}

static __device__ __forceinline__ f32x4 mfma16(short8s a, short8s b, f32x4 c) {
    return __builtin_amdgcn_mfma_f32_16x16x32_bf16(
        __builtin_bit_cast(bf16x8, a), __builtin_bit_cast(bf16x8, b), c, 0, 0, 0);
}

// ---------------- timestep embedding MLP (tiny: B=2) ----------------
__global__ void t_emb_kernel(const int* __restrict__ n,
                             const float* __restrict__ te_w1, const float* __restrict__ te_b1,
                             const float* __restrict__ te_w2, const float* __restrict__ te_b2,
                             float* __restrict__ t_emb) {
    const int b = blockIdx.x;
    const int t = threadIdx.x; // 128 threads
    __shared__ float emb[Dc];
    __shared__ float hid[4 * Dc];
    const float nf = (float)n[b];
    const int half = Dc / 2;
    {
        int j = (t < half) ? t : (t - half);
        float freq = expf(-logf(10000.0f) * (float)j / (float)half);
        float arg = nf * freq;
        emb[t] = (t < half) ? sinf(arg) : cosf(arg);
    }
    __syncthreads();
    for (int jj = 0; jj < 4; ++jj) {
        int c = t + jj * Dc;
        float acc = te_b1[c];
        for (int k = 0; k < Dc; ++k) acc += emb[k] * te_w1[k * (4 * Dc) + c];
        hid[c] = acc / (1.0f + expf(-acc));
    }
    __syncthreads();
    float acc = te_b2[t];
    for (int k = 0; k < 4 * Dc; ++k) acc += hid[k] * te_w2[k * Dc + t];
    t_emb[b * Dc + t] = acc;
}

// ---------------- input projection + t_emb add ----------------
__global__ void input_proj_kernel(const float* __restrict__ delta,
                                  const float* __restrict__ w_in, const float* __restrict__ b_in,
                                  const float* __restrict__ t_emb,
                                  float* __restrict__ h) {
    int idx = blockIdx.x * blockDim.x + threadIdx.x;
    const int total = Bc * Ec * (Dc / 4);
    if (idx >= total) return;
    int dq = idx & (Dc / 4 - 1);
    int be = idx >> 5;
    int b = be / Ec;
    const float* dd = delta + (size_t)be * 3;
    float d0 = dd[0], d1 = dd[1], d2 = dd[2];
    float4 acc = ((const float4*)b_in)[dq];
    float4 te = ((const float4*)t_emb)[b * (Dc / 4) + dq];
    float4 w0 = ((const float4*)w_in)[dq];
    float4 w1 = ((const float4*)w_in)[(Dc / 4) + dq];
    float4 w2 = ((const float4*)w_in)[2 * (Dc / 4) + dq];
    acc.x += te.x + d0 * w0.x + d1 * w1.x + d2 * w2.x;
    acc.y += te.y + d0 * w0.y + d1 * w1.y + d2 * w2.y;
    acc.z += te.z + d0 * w0.z + d1 * w1.z + d2 * w2.z;
    acc.w += te.w + d0 * w0.w + d1 * w1.w + d2 * w2.w;
    ((float4*)h)[idx] = acc;
}

// ---------------- weight pre-convert: fp32 -> bf16 transposed ----------------
__global__ void convert_w_kernel(const float* __restrict__ W1, const float* __restrict__ W2,
                                 short* __restrict__ w1t, short* __restrict__ w2t) {
    int idx = blockIdx.x * blockDim.x + threadIdx.x;
    if (idx < Lc * 128 * 256) {
        int l = idx / (128 * 256);
        int r = idx - l * (128 * 256);
        int nn = r >> 8;          // 0..127
        int k = r & 255;          // 0..255
        w1t[idx] = f2bf(W1[(size_t)l * 256 * 128 + k * 128 + nn]);
    }
    if (idx < Lc * 128 * 128) {
        int l = idx / (128 * 128);
        int r = idx - l * (128 * 128);
        int nn = r >> 7;
        int k = r & 127;
        w2t[idx] = f2bf(W2[(size_t)l * 128 * 128 + k * 128 + nn]);
    }
}

// ---------------- CSR build ----------------
__global__ void csr_zero_kernel(int* __restrict__ cnt) {
    int i = blockIdx.x * blockDim.x + threadIdx.x;
    if (i < Vc) cnt[i] = 0;
}

__global__ void csr_count_kernel(const int* __restrict__ src, const int* __restrict__ dst,
                                 int* __restrict__ cnt) {
    int i = blockIdx.x * blockDim.x + threadIdx.x;
    if (i >= 2 * Ec) return;
    int v = (i < Ec) ? src[i] : dst[i - Ec];
    atomicAdd(&cnt[v], 1);
}

// single-block exclusive scan over Vc entries -> off[0..Vc], cur copy
__global__ void csr_scan_kernel(const int* __restrict__ cnt,
                                int* __restrict__ off, int* __restrict__ cur) {
    __shared__ int part[256];
    const int t = threadIdx.x;
    const int CH = (Vc + 255) / 256; // 49
    int s = 0;
    for (int j = 0; j < CH; ++j) {
        int i = t * CH + j;
        if (i < Vc) s += cnt[i];
    }
    part[t] = s;
    __syncthreads();
    for (int ofs = 1; ofs < 256; ofs <<= 1) {
        int y = (t >= ofs) ? part[t - ofs] : 0;
        __syncthreads();
        part[t] += y;
        __syncthreads();
    }
    int run = part[t] - s; // exclusive base for this chunk
    for (int j = 0; j < CH; ++j) {
        int i = t * CH + j;
        if (i < Vc) {
            off[i] = run;
            cur[i] = run;
            run += cnt[i];
        }
    }
    if (t == 255) off[Vc] = run;
}

__global__ void csr_fill_kernel(const int* __restrict__ src, const int* __restrict__ dst,
                                int* __restrict__ cur, int* __restrict__ adj) {
    int i = blockIdx.x * blockDim.x + threadIdx.x;
    if (i >= 2 * Ec) return;
    int e = (i < Ec) ? i : (i - Ec);
    int v = (i < Ec) ? src[e] : dst[e];
    int p = atomicAdd(&cur[v], 1);
    adj[p] = e;
}

// ---------------- gather edges -> vertices (replaces zero+scatter) ----------------
// one wave per (b, v); lanes own 2 channels; writes vf as bf16
__global__ void gather_kernel(const float* __restrict__ h,
                              const int* __restrict__ off, const int* __restrict__ adj,
                              short* __restrict__ vf) {
    int gw = blockIdx.x * 4 + (threadIdx.x >> 6);
    if (gw >= Bc * Vc) return;
    int b = (gw >= Vc) ? 1 : 0;
    int v = gw - b * Vc;
    int lane = threadIdx.x & 63;
    int o0 = off[v], o1 = off[v + 1];
    const float2* hb = (const float2*)(h + (size_t)b * Ec * Dc);
    float2 acc = make_float2(0.f, 0.f);
    for (int j = o0; j < o1; ++j) {
        int e = adj[j];
        float2 x = hb[(size_t)e * (Dc / 2) + lane];
        acc.x += x.x;
        acc.y += x.y;
    }
    short2 w;
    w.x = f2bf(acc.x);
    w.y = f2bf(acc.y);
    ((short2*)vf)[(size_t)gw * (Dc / 2) + lane] = w;
}

// ---------------- fused edge MLP layer (MFMA bf16) ----------------
#define XSTR 264   // xin row stride (bf16 elems): 256 + 8 pad
#define X1STR 136  // x1s row stride: 128 + 8 pad
__launch_bounds__(256, 3)
__global__ void edge_layer_kernel(float* __restrict__ h,
                                  const short* __restrict__ vf,
                                  const int* __restrict__ src, const int* __restrict__ dst,
                                  const short* __restrict__ w1t, const float* __restrict__ b1,
                                  const float* __restrict__ ln_g, const float* __restrict__ ln_b,
                                  const short* __restrict__ w2t, const float* __restrict__ b2,
                                  const float* __restrict__ ng, const float* __restrict__ nb) {
    __shared__ short xin[64][XSTR];
    __shared__ short x1s[64][X1STR];

    const int t = threadIdx.x;
    const int w = t >> 6;
    const int lane = t & 63;
    const int m0 = w * 16;          // wave's edge sub-tile
    const int r = lane & 15;
    const int g = lane >> 4;        // k-block / reg-group

    // ---- stage gathered rows [vf[src] | vf[dst]] (bf16 direct copy)
    for (int it = 0; it < 16; ++it) {
        int m = m0 + it;
        int eg = blockIdx.x * 64 + m;
        int b = eg / Ec;
        int e = eg - b * Ec;
        int v = (lane < 32) ? src[e] : dst[e];
        const short4* vrow = (const short4*)(vf + ((size_t)(b * Vc + v)) * Dc);
        short4 s4 = vrow[lane & 31];
        *(short4*)&xin[m][4 * lane] = s4;
    }
    __syncthreads();

    // ---- GEMM1t: x1^T = W1^T (128x256) @ xin^T (256x16)
    f32x4 acc[8];
    #pragma unroll
    for (int nt = 0; nt < 8; ++nt) acc[nt] = (f32x4){0.f, 0.f, 0.f, 0.f};
    #pragma unroll 2
    for (int ks = 0; ks < 8; ++ks) {
        short8s bfrag = *(const short8s*)&xin[m0 + r][32 * ks + 8 * g];
        #pragma unroll
        for (int nt = 0; nt < 8; ++nt) {
            short8s afrag = *(const short8s*)(w1t + (size_t)(nt * 16 + r) * 256 + 32 * ks + 8 * g);
            acc[nt] = mfma16(afrag, bfrag, acc[nt]);
        }
    }

    // ---- bias + LN + silu; repack to bf16 LDS (row-major [m][k]) for GEMM2
    {
        float s = 0.f, ss = 0.f;
        #pragma unroll
        for (int nt = 0; nt < 8; ++nt) {
            const float4 bb = *(const float4*)&b1[nt * 16 + 4 * g];
            acc[nt][0] += bb.x; acc[nt][1] += bb.y; acc[nt][2] += bb.z; acc[nt][3] += bb.w;
            #pragma unroll
            for (int i = 0; i < 4; ++i) { float v = acc[nt][i]; s += v; ss += v * v; }
        }
        s += __shfl_xor(s, 16); ss += __shfl_xor(ss, 16);
        s += __shfl_xor(s, 32); ss += __shfl_xor(ss, 32);
        float mean = s * (1.0f / Dc);
        float var = ss * (1.0f / Dc) - mean * mean;
        float rstd = rsqrtf(var + 1e-5f);
        #pragma unroll
        for (int nt = 0; nt < 8; ++nt) {
            const float4 lg = *(const float4*)&ln_g[nt * 16 + 4 * g];
            const float4 lb = *(const float4*)&ln_b[nt * 16 + 4 * g];
            float o[4];
            #pragma unroll
            for (int i = 0; i < 4; ++i) {
                float gg = (i == 0) ? lg.x : (i == 1) ? lg.y : (i == 2) ? lg.z : lg.w;
                float bb = (i == 0) ? lb.x : (i == 1) ? lb.y : (i == 2) ? lb.z : lb.w;
                float xh = (acc[nt][i] - mean) * rstd * gg + bb;
                o[i] = xh / (1.0f + __expf(-xh));
            }
            short4 st;
            st.x = f2bf(o[0]); st.y = f2bf(o[1]); st.z = f2bf(o[2]); st.w = f2bf(o[3]);
            *(short4*)&x1s[m0 + r][nt * 16 + 4 * g] = st;
        }
    }
    __syncthreads();

    // ---- GEMM2t: x2^T = W2^T (128x128) @ x1^T (128x16)
    f32x4 acc2[8];
    #pragma unroll
    for (int nt = 0; nt < 8; ++nt) acc2[nt] = (f32x4){0.f, 0.f, 0.f, 0.f};
    #pragma unroll 2
    for (int ks = 0; ks < 4; ++ks) {
        short8s bfrag = *(const short8s*)&x1s[m0 + r][32 * ks + 8 * g];
        #pragma unroll
        for (int nt = 0; nt < 8; ++nt) {
            short8s afrag = *(const short8s*)(w2t + (size_t)(nt * 16 + r) * 128 + 32 * ks + 8 * g);
            acc2[nt] = mfma16(afrag, bfrag, acc2[nt]);
        }
    }

    // ---- bias + residual + LN -> h
    {
        float* hrow = h + (size_t)(blockIdx.x * 64 + m0 + r) * Dc;
        float s = 0.f, ss = 0.f;
        #pragma unroll
        for (int nt = 0; nt < 8; ++nt) {
            const float4 bb = *(const float4*)&b2[nt * 16 + 4 * g];
            const float4 hv = *(const float4*)(hrow + nt * 16 + 4 * g);
            acc2[nt][0] += bb.x + hv.x; acc2[nt][1] += bb.y + hv.y;
            acc2[nt][2] += bb.z + hv.z; acc2[nt][3] += bb.w + hv.w;
            #pragma unroll
            for (int i = 0; i < 4; ++i) { float v = acc2[nt][i]; s += v; ss += v * v; }
        }
        s += __shfl_xor(s, 16); ss += __shfl_xor(ss, 16);
        s += __shfl_xor(s, 32); ss += __shfl_xor(ss, 32);
        float mean = s * (1.0f / Dc);
        float var = ss * (1.0f / Dc) - mean * mean;
        float rstd = rsqrtf(var + 1e-5f);
        #pragma unroll
        for (int nt = 0; nt < 8; ++nt) {
            const float4 gv = *(const float4*)&ng[nt * 16 + 4 * g];
            const float4 bv = *(const float4*)&nb[nt * 16 + 4 * g];
            float4 o;
            o.x = (acc2[nt][0] - mean) * rstd * gv.x + bv.x;
            o.y = (acc2[nt][1] - mean) * rstd * gv.y + bv.y;
            o.z = (acc2[nt][2] - mean) * rstd * gv.z + bv.z;
            o.w = (acc2[nt][3] - mean) * rstd * gv.w + bv.w;
            *(float4*)(hrow + nt * 16 + 4 * g) = o;
        }
    }
}

// ---------------- output projection ----------------
__global__ void out_proj_kernel(const float* __restrict__ h,
                                const float* __restrict__ w_out, const float* __restrict__ b_out,
                                float* __restrict__ out) {
    int be = blockIdx.x * blockDim.x + threadIdx.x;
    if (be >= Bc * Ec) return;
    const float4* hp = (const float4*)(h + (size_t)be * Dc);
    float a0 = b_out[0], a1 = b_out[1], a2 = b_out[2];
    for (int q = 0; q < Dc / 4; ++q) {
        float4 v = hp[q];
        int k = q * 4;
        a0 += v.x * w_out[(k + 0) * 3 + 0] + v.y * w_out[(k + 1) * 3 + 0] +
              v.z * w_out[(k + 2) * 3 + 0] + v.w * w_out[(k + 3) * 3 + 0];
        a1 += v.x * w_out[(k + 0) * 3 + 1] + v.y * w_out[(k + 1) * 3 + 1] +
              v.z * w_out[(k + 2) * 3 + 1] + v.w * w_out[(k + 3) * 3 + 1];
        a2 += v.x * w_out[(k + 0) * 3 + 2] + v.y * w_out[(k + 1) * 3 + 2] +
              v.z * w_out[(k + 2) * 3 + 2] + v.w * w_out[(k + 3) * 3 + 2];
    }
    out[be * 3 + 0] = a0;
    out[be * 3 + 1] = a1;
    out[be * 3 + 2] = a2;
}

extern "C" void kernel_launch(void* const* d_in, const int* in_sizes, int n_in,
                              void* d_out, int out_size, void* d_ws, size_t ws_size,
                              hipStream_t stream) {
    const float* delta = (const float*)d_in[0];
    const int* n = (const int*)d_in[1];
    const int* edge_index = (const int*)d_in[2];
    const float* w_in = (const float*)d_in[4];
    const float* b_in = (const float*)d_in[5];
    const float* W1 = (const float*)d_in[6];
    const float* b1 = (const float*)d_in[7];
    const float* ln_g = (const float*)d_in[8];
    const float* ln_b = (const float*)d_in[9];
    const float* W2 = (const float*)d_in[10];
    const float* b2 = (const float*)d_in[11];
    const float* ng = (const float*)d_in[12];
    const float* nb = (const float*)d_in[13];
    const float* te_w1 = (const float*)d_in[14];
    const float* te_b1 = (const float*)d_in[15];
    const float* te_w2 = (const float*)d_in[16];
    const float* te_b2 = (const float*)d_in[17];
    const float* w_out = (const float*)d_in[18];
    const float* b_out = (const float*)d_in[19];
    float* out = (float*)d_out;

    // ---- workspace layout (all 256B-aligned) ----
    char* ws = (char*)d_ws;
    size_t o = 0;
    float* t_emb = (float*)(ws + o); o += 1024;
    float* h     = (float*)(ws + o); o += (size_t)Bc * Ec * Dc * 4;        // 102.4 MB
    short* vf    = (short*)(ws + o); o += (size_t)Bc * Vc * Dc * 2;        // 6.4 MB
    short* w1t   = (short*)(ws + o); o += (size_t)Lc * 128 * 256 * 2;
    short* w2t   = (short*)(ws + o); o += (size_t)Lc * 128 * 128 * 2;
    int* cnt     = (int*)(ws + o);   o += ((size_t)Vc * 4 + 255) / 256 * 256;
    int* off     = (int*)(ws + o);   o += ((size_t)(Vc + 1) * 4 + 255) / 256 * 256;
    int* cur     = (int*)(ws + o);   o += ((size_t)Vc * 4 + 255) / 256 * 256;
    int* adj     = (int*)(ws + o);   o += (size_t)2 * Ec * 4;              // 800 KB

    const int* src = edge_index;
    const int* dst = edge_index + Ec;

    t_emb_kernel<<<Bc, Dc, 0, stream>>>(n, te_w1, te_b1, te_w2, te_b2, t_emb);
    convert_w_kernel<<<(Lc * 128 * 256 + 255) / 256, 256, 0, stream>>>(W1, W2, w1t, w2t);

    {
        int total = Bc * Ec * (Dc / 4);
        input_proj_kernel<<<(total + 255) / 256, 256, 0, stream>>>(delta, w_in, b_in, t_emb, h);
    }

    // CSR build (once per call)
    csr_zero_kernel<<<(Vc + 255) / 256, 256, 0, stream>>>(cnt);
    csr_count_kernel<<<(2 * Ec + 255) / 256, 256, 0, stream>>>(src, dst, cnt);
    csr_scan_kernel<<<1, 256, 0, stream>>>(cnt, off, cur);
    csr_fill_kernel<<<(2 * Ec + 255) / 256, 256, 0, stream>>>(src, dst, cur, adj);

    for (int i = 0; i < Lc; ++i) {
        gather_kernel<<<(Bc * Vc + 3) / 4, 256, 0, stream>>>(h, off, adj, vf);
        edge_layer_kernel<<<(Bc * Ec) / 64, 256, 0, stream>>>(
            h, vf, src, dst,
            w1t + (size_t)i * 128 * 256, b1 + i * Dc,
            ln_g + i * Dc, ln_b + i * Dc,
            w2t + (size_t)i * 128 * 128, b2 + i * Dc,
            ng + i * Dc, nb + i * Dc);
    }

    out_proj_kernel<<<(Bc * Ec + 255) / 256, 256, 0, stream>>>(h, w_out, b_out, out);
}